// Round 1
// baseline (553.969 us; speedup 1.0000x reference)
//
#include <hip/hip_runtime.h>

#define BTOT 4096
#define TS 32
#define NB 4          // batch elements per LSTM block

struct LstmP {
  const float* x[6];
  const float* wih[6];
  const float* whh[6];
  const float* bias[6];
  float* hout;        // [6][BTOT][64]
};

struct EpiP {
  const float* hout;
  const float* s2;
  const float* w03[2]; const float* b03[2];
  const float* w1[2];  const float* b1[2];
  const float* w2[2];  const float* b2[2];
  float* out;
};

__device__ __forceinline__ float sigf(float v){ return 1.0f/(1.0f + __expf(-v)); }
__device__ __forceinline__ float tanhf_(float v){ return 2.0f/(1.0f + __expf(-2.0f*v)) - 1.0f; }

// Each block: one LSTM run (blockIdx.y), NB=4 batch elems (blockIdx.x).
// Thread t: gate-compute role = whh rows u=t&127 and u+128 held in 128 VGPRs,
// computes those 2 gates for 2 elems (eg=t>>7 selects elems {2eg,2eg+1}).
// Update role: (ue=t>>6, uj=t&63) owns c[ue][uj] in a register.
__global__ __launch_bounds__(256) void lstm6(LstmP p){
  const int run = blockIdx.y;
  const int t = threadIdx.x;
  const int b0 = blockIdx.x * NB;
  const int u  = t & 127;
  const int eg = t >> 7;

  __shared__ float4 h4[NB*16];       // h[4][64] as float4
  __shared__ float gates[NB*256];
  __shared__ float xs[NB*TS];

  const float* __restrict__ whh = p.whh[run];
  const float* __restrict__ x   = p.x[run];

  float4 w0[16], w1[16];
  {
    const float4* r0 = (const float4*)(whh + u*64);
    const float4* r1 = (const float4*)(whh + (u+128)*64);
#pragma unroll
    for (int kk=0; kk<16; ++kk){ w0[kk]=r0[kk]; w1[kk]=r1[kk]; }
  }
  const float wih0 = p.wih[run][u];
  const float wih1 = p.wih[run][u+128];
  const float bv0  = p.bias[run][u];
  const float bv1  = p.bias[run][u+128];

  if (t < NB*TS){
    int e = t >> 5, s = t & 31;
    xs[e*TS+s] = x[(size_t)(b0+e)*TS + s];
  }
  ((float*)h4)[t] = 0.0f;   // h init (NB*64 == 256)

  const int ue = t >> 6, uj = t & 63;
  float c = 0.0f, hval = 0.0f;

  const float4* hA = h4 + (2*eg)*16;
  const float4* hB = h4 + (2*eg+1)*16;

  for (int s=0; s<TS; ++s){
    __syncthreads();    // h from previous step visible
    float a00=0.f, a01=0.f, a10=0.f, a11=0.f;
#pragma unroll
    for (int kk=0; kk<16; ++kk){
      float4 ha = hA[kk], hb = hB[kk];     // broadcast reads (wave-uniform addr)
      float4 wa = w0[kk], wb = w1[kk];
      a00 = fmaf(ha.x, wa.x, a00); a01 = fmaf(ha.x, wb.x, a01);
      a10 = fmaf(hb.x, wa.x, a10); a11 = fmaf(hb.x, wb.x, a11);
      a00 = fmaf(ha.y, wa.y, a00); a01 = fmaf(ha.y, wb.y, a01);
      a10 = fmaf(hb.y, wa.y, a10); a11 = fmaf(hb.y, wb.y, a11);
      a00 = fmaf(ha.z, wa.z, a00); a01 = fmaf(ha.z, wb.z, a01);
      a10 = fmaf(hb.z, wa.z, a10); a11 = fmaf(hb.z, wb.z, a11);
      a00 = fmaf(ha.w, wa.w, a00); a01 = fmaf(ha.w, wb.w, a01);
      a10 = fmaf(hb.w, wa.w, a10); a11 = fmaf(hb.w, wb.w, a11);
    }
    float xv0 = xs[(2*eg)*TS + s], xv1 = xs[(2*eg+1)*TS + s];
    gates[(2*eg)*256 + u]         = fmaf(wih0, xv0, a00) + bv0;
    gates[(2*eg)*256 + 128 + u]   = fmaf(wih1, xv0, a01) + bv1;
    gates[(2*eg+1)*256 + u]       = fmaf(wih0, xv1, a10) + bv0;
    gates[(2*eg+1)*256 + 128 + u] = fmaf(wih1, xv1, a11) + bv1;
    __syncthreads();
    // PyTorch gate order: i, f, g, o
    float gi = gates[ue*256 + uj];
    float gf = gates[ue*256 + 64 + uj];
    float gg = gates[ue*256 + 128 + uj];
    float go = gates[ue*256 + 192 + uj];
    c = sigf(gf)*c + sigf(gi)*tanhf_(gg);
    hval = sigf(go)*tanhf_(c);
    ((float*)h4)[ue*64 + uj] = hval;
  }
  p.hout[((size_t)run*BTOT + b0 + ue)*64 + uj] = hval;
}

// Epilogue: grid (BTOT/4, 2). blockIdx.y = branch (0=q, 1=i).
// Thread: e = t>>6 (elem 0..3), j = t&63.
__global__ __launch_bounds__(256) void epilogue(EpiP p){
  const int br = blockIdx.y;
  const int t = threadIdx.x;
  const int e = t >> 6, j = t & 63;
  const int b = blockIdx.x*4 + e;

  __shared__ float hq[4][256];
  __shared__ float qv[4][64];
  __shared__ float iv[4][8];

  const float* hbase = p.hout + (size_t)br*3*BTOT*64;
  hq[e][j]      = hbase[((size_t)0*BTOT + b)*64 + j];
  hq[e][64+j]   = hbase[((size_t)1*BTOT + b)*64 + j];
  hq[e][128+j]  = hbase[((size_t)2*BTOT + b)*64 + j];
  {
    const float* w03 = p.w03[br];
    float s0 = p.s2[b*3+0], s1 = p.s2[b*3+1], s2v = p.s2[b*3+2];
    float hn3 = s0*w03[j*3+0] + s1*w03[j*3+1] + s2v*w03[j*3+2] + p.b03[br][j];
    hq[e][192+j] = fmaxf(hn3, 0.0f);
  }
  __syncthreads();
  {
    const float4* w1r = (const float4*)(p.w1[br] + j*256);
    const float4* hqe = (const float4*)(&hq[e][0]);
    float acc = p.b1[br][j];
#pragma unroll 8
    for (int kk=0; kk<64; ++kk){
      float4 w = w1r[kk]; float4 h = hqe[kk];
      acc = fmaf(w.x,h.x, fmaf(w.y,h.y, fmaf(w.z,h.z, fmaf(w.w,h.w, acc))));
    }
    qv[e][j] = fmaxf(acc, 0.0f);
  }
  __syncthreads();
  if (t < 24){
    int ee = t / 6, a = t % 6;
    const float* w2r = p.w2[br] + a*64;
    const float* qe = &qv[ee][0];
    float acc2 = p.b2[br][a];
    for (int k=0;k<64;++k) acc2 = fmaf(qe[k], w2r[k], acc2);
    int bb = blockIdx.x*4 + ee;
    if (br == 0){
      p.out[(size_t)bb*6 + a] = acc2;                 // q output (no relu)
    } else {
      float v = fmaxf(acc2, 0.0f);
      iv[ee][a] = v;
      p.out[(size_t)2*BTOT*6 + (size_t)bb*6 + a] = v; // third output: i
    }
  }
  __syncthreads();
  if (br == 1 && t < 4){
    int bb = blockIdx.x*4 + t;
    float m = iv[t][0];
    for (int a=1;a<6;++a) m = fmaxf(m, iv[t][a]);
    float ssum = 0.0f;
    for (int a=0;a<6;++a) ssum += __expf(iv[t][a]-m);
    float ls = __logf(ssum);
    for (int a=0;a<6;++a)
      p.out[(size_t)BTOT*6 + (size_t)bb*6 + a] = iv[t][a] - m - ls;
  }
}

extern "C" void kernel_launch(void* const* d_in, const int* in_sizes, int n_in,
                              void* d_out, int out_size, void* d_ws, size_t ws_size,
                              hipStream_t stream) {
  const float* x0 = (const float*)d_in[0];
  const float* x1 = (const float*)d_in[1];
  const float* x2 = (const float*)d_in[2];
  const float* s2 = (const float*)d_in[3];

  LstmP lp;
  lp.x[0]=x0; lp.x[1]=x1; lp.x[2]=x2; lp.x[3]=x0; lp.x[4]=x1; lp.x[5]=x2;
  const int wbase[6] = {4, 7, 7, 10, 13, 16};   // q00, q01, q01, i00, i01, i02
  for (int r=0;r<6;++r){
    lp.wih[r]  = (const float*)d_in[wbase[r]+0];
    lp.whh[r]  = (const float*)d_in[wbase[r]+1];
    lp.bias[r] = (const float*)d_in[wbase[r]+2];
  }
  lp.hout = (float*)d_ws;   // 6*4096*64 floats = 6.29 MB

  lstm6<<<dim3(BTOT/NB, 6), 256, 0, stream>>>(lp);

  EpiP ep;
  ep.hout = (const float*)d_ws;
  ep.s2 = s2;
  ep.w03[0]=(const float*)d_in[19]; ep.b03[0]=(const float*)d_in[20];
  ep.w1 [0]=(const float*)d_in[21]; ep.b1 [0]=(const float*)d_in[22];
  ep.w2 [0]=(const float*)d_in[23]; ep.b2 [0]=(const float*)d_in[24];
  ep.w03[1]=(const float*)d_in[25]; ep.b03[1]=(const float*)d_in[26];
  ep.w1 [1]=(const float*)d_in[27]; ep.b1 [1]=(const float*)d_in[28];
  ep.w2 [1]=(const float*)d_in[29]; ep.b2 [1]=(const float*)d_in[30];
  ep.out = (float*)d_out;

  epilogue<<<dim3(BTOT/4, 2), 256, 0, stream>>>(ep);
}

// Round 3
// 236.027 us; speedup vs baseline: 2.3471x; 2.3471x over previous
//
#include <hip/hip_runtime.h>

#define BTOT 4096
#define TS 32

typedef __attribute__((ext_vector_type(8))) short bfrag;   // 8 bf16, 16 B
typedef __attribute__((ext_vector_type(4))) float f32x4;

__device__ __forceinline__ short f2bf(float f){
  union { float f; unsigned u; } v; v.f = f;
  unsigned r = v.u + 0x7FFFu + ((v.u >> 16) & 1u);   // RNE
  return (short)(r >> 16);
}
__device__ __forceinline__ float bf2f(short s){
  union { unsigned u; float f; } v; v.u = ((unsigned)(unsigned short)s) << 16; return v.f;
}
__device__ __forceinline__ float sigf(float v){
  return __builtin_amdgcn_rcpf(1.0f + __expf(-v));
}
__device__ __forceinline__ float tanhf_(float v){
  // tanh(v) = 1 - 2/(1+e^{2v})
  return fmaf(-2.0f, __builtin_amdgcn_rcpf(1.0f + __expf(2.0f * v)), 1.0f);
}

struct LstmP {
  const float* x[6];
  const float* wih[6];
  const float* whh[6];
  const float* bias[6];
  float* hout;        // [6][BTOT][64] fp32
};

struct EpiP {
  const float* hout;
  const float* s2;
  const float* w03[2]; const float* b03[2];
  const float* w1[2];  const float* b1[2];
  const float* w2[2];  const float* b2[2];
  float* out;
};

// Block: run = blockIdx.y, 16 batch elems. 4 waves.
// Wave w owns n-tiles {w, w+4, w+8, w+12} -> lane holds i,f,g,o of cell
// (m = 4*(lane>>4)+r, j = 16*w + (lane&15)) entirely in C-registers.
// h round-trips LDS as split bf16 (hi/lo), double-buffered, 1 barrier/step.
// LDS h-buffer is typed as bfrag (16B) so ds_read_b128 alignment is guaranteed.
__global__ __launch_bounds__(256) void lstm6(LstmP p){
  const int run = blockIdx.y;
  const int b0 = blockIdx.x * 16;
  const int t = threadIdx.x;
  const int wave = t >> 6, lane = t & 63;
  const int i16 = lane & 15, q = lane >> 4;

  // [parity][hi/lo][16 rows * 9 frags]; row stride 9 frags = 72 shorts (pad)
  __shared__ bfrag hbufv[2][2][16*9];
  __shared__ float xs[16*33];           // [m][s], stride 33 (pad)

  const float* __restrict__ whh = p.whh[run];

  // Whh B-fragments, split hi/lo, held in VGPRs.
  bfrag Bhi[4][2], Blo[4][2];
#pragma unroll
  for (int g = 0; g < 4; ++g){
    int n = 16*(4*g + wave) + i16;               // whh row (gate index)
    const float* wr = whh + n*64;
#pragma unroll
    for (int ks = 0; ks < 2; ++ks){
      const float* src = wr + 32*ks + 8*q;       // 8 consecutive k
      bfrag bh, bl;
#pragma unroll
      for (int j = 0; j < 8; ++j){
        float f = src[j];
        short hi = f2bf(f);
        bh[j] = hi;
        bl[j] = f2bf(f - bf2f(hi));
      }
      Bhi[g][ks] = bh; Blo[g][ks] = bl;
    }
  }
  float wihv[4], bv[4];
#pragma unroll
  for (int g = 0; g < 4; ++g){
    int n = 64*g + 16*wave + i16;
    wihv[g] = p.wih[run][n];
    bv[g]   = p.bias[run][n];
  }
  {
    const float* x = p.x[run] + (size_t)b0 * TS;
    for (int i = t; i < 16*TS; i += 256) xs[(i>>5)*33 + (i&31)] = x[i];
    int* hz = (int*)&hbufv[0][0][0];            // zero parity-0 hi+lo
    for (int i = t; i < 1152; i += 256) hz[i] = 0;
  }
  __syncthreads();

  float c[4] = {0.f,0.f,0.f,0.f};
  float hlast[4] = {0.f,0.f,0.f,0.f};

  for (int s = 0; s < TS; ++s){
    const bfrag* hh = hbufv[s & 1][0];
    const bfrag* hl = hbufv[s & 1][1];
    const int af = i16*9 + q;                    // A: m=lane&15, k=8q+j
    bfrag ah0 = hh[af];
    bfrag ah1 = hh[af + 4];
    bfrag al0 = hl[af];
    bfrag al1 = hl[af + 4];
    float xm[4];
#pragma unroll
    for (int r = 0; r < 4; ++r) xm[r] = xs[(4*q + r)*33 + s];

    f32x4 acc[4];
#pragma unroll
    for (int g = 0; g < 4; ++g){
#pragma unroll
      for (int r = 0; r < 4; ++r) acc[g][r] = fmaf(xm[r], wihv[g], bv[g]);
      acc[g] = __builtin_amdgcn_mfma_f32_16x16x32_bf16(ah0, Bhi[g][0], acc[g], 0,0,0);
      acc[g] = __builtin_amdgcn_mfma_f32_16x16x32_bf16(ah1, Bhi[g][1], acc[g], 0,0,0);
      acc[g] = __builtin_amdgcn_mfma_f32_16x16x32_bf16(al0, Bhi[g][0], acc[g], 0,0,0);
      acc[g] = __builtin_amdgcn_mfma_f32_16x16x32_bf16(al1, Bhi[g][1], acc[g], 0,0,0);
      acc[g] = __builtin_amdgcn_mfma_f32_16x16x32_bf16(ah0, Blo[g][0], acc[g], 0,0,0);
      acc[g] = __builtin_amdgcn_mfma_f32_16x16x32_bf16(ah1, Blo[g][1], acc[g], 0,0,0);
    }

    short* whi = (short*)hbufv[(s+1) & 1][0];
    short* wlo = (short*)hbufv[(s+1) & 1][1];
#pragma unroll
    for (int r = 0; r < 4; ++r){
      float gi = acc[0][r], gf = acc[1][r], gg = acc[2][r], go = acc[3][r];
      float cc = sigf(gf)*c[r] + sigf(gi)*tanhf_(gg);
      c[r] = cc;
      float hv = sigf(go)*tanhf_(cc);
      hlast[r] = hv;
      int off = (4*q + r)*72 + 16*wave + i16;
      short hi = f2bf(hv);
      whi[off] = hi;
      wlo[off] = f2bf(hv - bf2f(hi));
    }
    __syncthreads();
  }

#pragma unroll
  for (int r = 0; r < 4; ++r){
    int m = 4*q + r, j = 16*wave + i16;
    p.hout[((size_t)run*BTOT + b0 + m)*64 + j] = hlast[r];
  }
}

// Epilogue: 16 batch / block, grid (256, 2). Layer1 (256->64) split-bf16 MFMA,
// layer2 (64->6) fp32 VALU, log_softmax for i-branch.
__global__ __launch_bounds__(256) void epilogue(EpiP p){
  const int br = blockIdx.y;
  const int b0 = blockIdx.x * 16;
  const int t = threadIdx.x;
  const int wave = t >> 6, lane = t & 63;
  const int i16 = lane & 15, q = lane >> 4;

  __shared__ bfrag hqv_hi[16*33], hqv_lo[16*33];   // [m][k], stride 33 frags = 264 shorts
  __shared__ float qv[16*66];                       // layer1 out, stride 66
  __shared__ float iv[16][6];

  const float* hbase = p.hout + (size_t)br*3*BTOT*64;
  // stage cols 0..191 from the 3 LSTM outputs (fp32 -> split bf16)
  {
    short4* dh = (short4*)hqv_hi;
    short4* dl = (short4*)hqv_lo;
    for (int i = t; i < 768; i += 256){
      int run = i >> 8, ii = i & 255;
      int e = ii >> 4, j4 = ii & 15;
      float4 v = *(const float4*)(hbase + ((size_t)run*BTOT + b0 + e)*64 + j4*4);
      short4 h, l;
      short x0 = f2bf(v.x); h.x = x0; l.x = f2bf(v.x - bf2f(x0));
      short x1 = f2bf(v.y); h.y = x1; l.y = f2bf(v.y - bf2f(x1));
      short x2 = f2bf(v.z); h.z = x2; l.z = f2bf(v.z - bf2f(x2));
      short x3 = f2bf(v.w); h.w = x3; l.w = f2bf(v.w - bf2f(x3));
      int o4 = e*66 + run*16 + j4;               // short4 units (264/4 = 66)
      dh[o4] = h;
      dl[o4] = l;
    }
  }
  // hn3 = relu(s2 @ w03^T + b03) -> cols 192..255
  {
    short* sh = (short*)hqv_hi;
    short* sl = (short*)hqv_lo;
    const float* w03 = p.w03[br];
    const float* b03 = p.b03[br];
    for (int i = t; i < 1024; i += 256){
      int e = i >> 6, jj = i & 63;
      const float* s2r = p.s2 + (size_t)(b0 + e)*3;
      float v = fmaf(s2r[0], w03[jj*3+0],
                fmaf(s2r[1], w03[jj*3+1],
                fmaf(s2r[2], w03[jj*3+2], b03[jj])));
      v = fmaxf(v, 0.0f);
      int off = e*264 + 192 + jj;
      short hi = f2bf(v);
      sh[off] = hi;
      sl[off] = f2bf(v - bf2f(hi));
    }
  }
  __syncthreads();

  // layer1: wave owns n-tile = wave -> output col n = 16*wave + i16
  {
    const int n = 16*wave + i16;
    const float* w1r = p.w1[br] + (size_t)n*256;
    f32x4 acc;
    { float bb = p.b1[br][n]; acc[0]=bb; acc[1]=bb; acc[2]=bb; acc[3]=bb; }
#pragma unroll
    for (int ks = 0; ks < 8; ++ks){
      bfrag ah = hqv_hi[i16*33 + 4*ks + q];
      bfrag al = hqv_lo[i16*33 + 4*ks + q];
      const float* src = w1r + 32*ks + 8*q;
      bfrag bh, bl;
#pragma unroll
      for (int j = 0; j < 8; ++j){
        float f = src[j];
        short hi = f2bf(f);
        bh[j] = hi;
        bl[j] = f2bf(f - bf2f(hi));
      }
      acc = __builtin_amdgcn_mfma_f32_16x16x32_bf16(ah, bh, acc, 0,0,0);
      acc = __builtin_amdgcn_mfma_f32_16x16x32_bf16(al, bh, acc, 0,0,0);
      acc = __builtin_amdgcn_mfma_f32_16x16x32_bf16(ah, bl, acc, 0,0,0);
    }
#pragma unroll
    for (int r = 0; r < 4; ++r)
      qv[(4*q + r)*66 + n] = fmaxf(acc[r], 0.0f);
  }
  __syncthreads();

  if (t < 96){
    int e = t / 6, a = t % 6;
    const float* w2r = p.w2[br] + a*64;
    const float* qe = qv + e*66;
    float acc2 = p.b2[br][a];
#pragma unroll 8
    for (int k = 0; k < 64; ++k) acc2 = fmaf(qe[k], w2r[k], acc2);
    int b = b0 + e;
    if (br == 0){
      p.out[(size_t)b*6 + a] = acc2;                       // q head, no relu
    } else {
      float v = fmaxf(acc2, 0.0f);
      iv[e][a] = v;
      p.out[(size_t)2*BTOT*6 + (size_t)b*6 + a] = v;       // i (third output)
    }
  }
  __syncthreads();
  if (br == 1 && t < 16){
    float m = iv[t][0];
    for (int a2 = 1; a2 < 6; ++a2) m = fmaxf(m, iv[t][a2]);
    float ss = 0.0f;
    for (int a2 = 0; a2 < 6; ++a2) ss += __expf(iv[t][a2] - m);
    float ls = __logf(ss);
    int b = b0 + t;
    for (int a2 = 0; a2 < 6; ++a2)
      p.out[(size_t)BTOT*6 + (size_t)b*6 + a2] = iv[t][a2] - m - ls;
  }
}

extern "C" void kernel_launch(void* const* d_in, const int* in_sizes, int n_in,
                              void* d_out, int out_size, void* d_ws, size_t ws_size,
                              hipStream_t stream) {
  const float* x0 = (const float*)d_in[0];
  const float* x1 = (const float*)d_in[1];
  const float* x2 = (const float*)d_in[2];
  const float* s2 = (const float*)d_in[3];

  LstmP lp;
  lp.x[0]=x0; lp.x[1]=x1; lp.x[2]=x2; lp.x[3]=x0; lp.x[4]=x1; lp.x[5]=x2;
  const int wbase[6] = {4, 7, 7, 10, 13, 16};   // q00, q01, q01, i00, i01, i02
  for (int r = 0; r < 6; ++r){
    lp.wih[r]  = (const float*)d_in[wbase[r]+0];
    lp.whh[r]  = (const float*)d_in[wbase[r]+1];
    lp.bias[r] = (const float*)d_in[wbase[r]+2];
  }
  lp.hout = (float*)d_ws;   // 6*4096*64 fp32 = 6.29 MB

  lstm6<<<dim3(BTOT/16, 6), 256, 0, stream>>>(lp);

  EpiP ep;
  ep.hout = (const float*)d_ws;
  ep.s2 = s2;
  ep.w03[0]=(const float*)d_in[19]; ep.b03[0]=(const float*)d_in[20];
  ep.w1 [0]=(const float*)d_in[21]; ep.b1 [0]=(const float*)d_in[22];
  ep.w2 [0]=(const float*)d_in[23]; ep.b2 [0]=(const float*)d_in[24];
  ep.w03[1]=(const float*)d_in[25]; ep.b03[1]=(const float*)d_in[26];
  ep.w1 [1]=(const float*)d_in[27]; ep.b1 [1]=(const float*)d_in[28];
  ep.w2 [1]=(const float*)d_in[29]; ep.b2 [1]=(const float*)d_in[30];
  ep.out = (float*)d_out;

  epilogue<<<dim3(BTOT/16, 2), 256, 0, stream>>>(ep);
}